// Round 4
// baseline (3746.844 us; speedup 1.0000x reference)
//
#include <hip/hip_runtime.h>
#include <hip/hip_bf16.h>

#define DD 2048
#define NF 24
#define NROWS 4096
#define VOCAB_N 32000
#define EPS_F 1.1920929e-07f

typedef __attribute__((ext_vector_type(8))) __bf16 bf16x8;
typedef __attribute__((ext_vector_type(4))) float f32x4;

__device__ __forceinline__ unsigned short f2bf(float f) {
  union { float f; unsigned int u; } v; v.f = f;
  unsigned int r = v.u + 0x7fffu + ((v.u >> 16) & 1u);  // RNE
  return (unsigned short)(r >> 16);
}

__device__ __forceinline__ void gload_lds16(const void* g, void* l) {
  __builtin_amdgcn_global_load_lds(
      (const __attribute__((address_space(1))) void*)g,
      (__attribute__((address_space(3))) void*)l, 16, 0, 0);
}

// ---------------- embedding gather ----------------
__global__ __launch_bounds__(256) void k_gather(const int* __restrict__ tok,
                                                const float* __restrict__ embed,
                                                float* __restrict__ x) {
  const int row = blockIdx.x;
  const int t = tok[row];
  const float4* s = (const float4*)(embed + (size_t)t * DD);
  float4* d = (float4*)(x + (size_t)row * DD);
  d[threadIdx.x] = s[threadIdx.x];
  d[threadIdx.x + 256] = s[threadIdx.x + 256];
}

// ---------------- W reconstruction (unchanged) ----------------
__global__ __launch_bounds__(256) void k_wrec(
    const float* __restrict__ hr, const float* __restrict__ hi,
    const float* __restrict__ kar, const float* __restrict__ kai,
    const float* __restrict__ kbr, const float* __restrict__ kbi,
    const float* __restrict__ scale, unsigned short* __restrict__ W) {
  __shared__ float HR[64][64], HI[64][64];
  __shared__ float AR[16][64], AI[16][64], BR[16][64], BI[16][64];
  const int e0 = blockIdx.x * 64, d0 = blockIdx.y * 64;
  const int tid = threadIdx.x;
  {
    const int r = tid >> 2, cbase = (tid & 3) * 16;
#pragma unroll
    for (int j = 0; j < 4; ++j) {
      const int c = cbase + j * 4;
      *(float4*)&HR[r][c] = *(const float4*)&hr[(size_t)(e0 + r) * DD + d0 + c];
      *(float4*)&HI[r][c] = *(const float4*)&hi[(size_t)(e0 + r) * DD + d0 + c];
    }
  }
  const int te = tid >> 4, td = tid & 15;
  for (int f = 0; f < NF; ++f) {
    __syncthreads();
    {
      const int r = tid >> 4, c = (tid & 15) * 4;
      const size_t ga = ((size_t)f * 16 + r) * DD;
      *(float4*)&AR[r][c] = *(const float4*)&kar[ga + e0 + c];
      *(float4*)&AI[r][c] = *(const float4*)&kai[ga + e0 + c];
      *(float4*)&BR[r][c] = *(const float4*)&kbr[ga + d0 + c];
      *(float4*)&BI[r][c] = *(const float4*)&kbi[ga + d0 + c];
    }
    __syncthreads();
    float pr[4][4], pi[4][4];
#pragma unroll
    for (int i = 0; i < 4; ++i)
#pragma unroll
      for (int j = 0; j < 4; ++j) { pr[i][j] = 0.f; pi[i][j] = 0.f; }
#pragma unroll 4
    for (int r = 0; r < 16; ++r) {
      float ar[4], ai[4], br[4], bi[4];
      *(float4*)ar = *(const float4*)&AR[r][te * 4];
      *(float4*)ai = *(const float4*)&AI[r][te * 4];
      *(float4*)br = *(const float4*)&BR[r][td * 4];
      *(float4*)bi = *(const float4*)&BI[r][td * 4];
#pragma unroll
      for (int i = 0; i < 4; ++i)
#pragma unroll
        for (int j = 0; j < 4; ++j) {
          pr[i][j] += ar[i] * br[j] + ai[i] * bi[j];
          pi[i][j] += ai[i] * br[j] - ar[i] * bi[j];
        }
    }
    const float sc = scale[f];
#pragma unroll
    for (int i = 0; i < 4; ++i) {
      const int e = te * 4 + i;
      ushort4 o;
      float w0 = (HR[e][td * 4 + 0] * pr[i][0] - HI[e][td * 4 + 0] * pi[i][0]) * sc;
      float w1 = (HR[e][td * 4 + 1] * pr[i][1] - HI[e][td * 4 + 1] * pi[i][1]) * sc;
      float w2 = (HR[e][td * 4 + 2] * pr[i][2] - HI[e][td * 4 + 2] * pi[i][2]) * sc;
      float w3 = (HR[e][td * 4 + 3] * pr[i][3] - HI[e][td * 4 + 3] * pi[i][3]) * sc;
      o.x = f2bf(w0); o.y = f2bf(w1); o.z = f2bf(w2); o.w = f2bf(w3);
      *(ushort4*)&W[((size_t)f * DD + e0 + e) * DD + d0 + td * 4] = o;
    }
  }
}

// ---------------- rmsnorm ----------------
__global__ __launch_bounds__(256) void k_rmsnorm(const float* __restrict__ x,
                                                 const float* __restrict__ w,
                                                 unsigned short* __restrict__ h) {
  const int row = blockIdx.x, tid = threadIdx.x;
  const float4* xr = (const float4*)(x + (size_t)row * DD);
  const float4 a = xr[tid], b = xr[tid + 256];
  float s = a.x * a.x + a.y * a.y + a.z * a.z + a.w * a.w +
            b.x * b.x + b.y * b.y + b.z * b.z + b.w * b.w;
#pragma unroll
  for (int m = 32; m; m >>= 1) s += __shfl_xor(s, m);
  __shared__ float part[4];
  if ((tid & 63) == 0) part[tid >> 6] = s;
  __syncthreads();
  const float inv = rsqrtf((part[0] + part[1] + part[2] + part[3]) * (1.f / DD) + EPS_F);
  const float4* wr = (const float4*)w;
  const float4 w0 = wr[tid], w1 = wr[tid + 256];
  ushort4 o0, o1;
  o0.x = f2bf(a.x * inv * w0.x); o0.y = f2bf(a.y * inv * w0.y);
  o0.z = f2bf(a.z * inv * w0.z); o0.w = f2bf(a.w * inv * w0.w);
  o1.x = f2bf(b.x * inv * w1.x); o1.y = f2bf(b.y * inv * w1.y);
  o1.z = f2bf(b.z * inv * w1.z); o1.w = f2bf(b.w * inv * w1.w);
  ushort4* hd = (ushort4*)(h + (size_t)row * DD);
  hd[tid] = o0;
  hd[tid + 256] = o1;
}

// ---------------- ring-6 pipelined GEMM ----------------
// out[t][n] (+)= act( sum_k A[t][k]*B[n][k] );  A:[M][2048] bf16, B:[N][2048] bf16.
// BM=128, BN=256, BK=32, 8 waves (2Mx4N), per-wave 64x64 (acc 4x4 frags).
// LDS ring of 6 K-tiles: A 6x8KB + B 6x16KB = 144KB. One phase per K-tile:
//   { stage tile t+5 (3 gload_lds16) | 8x ds_read_b128 (tile t) | vmcnt(12) |
//     barrier | setprio(1) 16x MFMA setprio(0) | barrier }
// vmcnt(12): stages for t+2..t+5 (12 loads) stay in flight; tile t+1 guaranteed
// landed (own-wave drain + barrier => cross-wave). Arrival slack for a staged
// tile ~4.3 phases (~1100 cyc at the 258-cyc MFMA-limited phase) > 900-cyc HBM
// miss latency. Overwrite: STAGE(t+5) writes slot (t-1); its ds_reads drained
// (lgkmcnt0) before MFMA(t-1) < barrier2(t-1) < phase t. Tail drains 12->9->6->3->0.
// Swizzle: LDS k-group s holds global k-group s ^ ((row>>1)&3) (pre-swizzled
// global source, linear gload dest, swizzled ds_read addr) -> 0 bank conflicts.
// ACT: 0 = C += v, 1 = C += silu(v), 2 = C = v
template <int ACT>
__global__ __launch_bounds__(512, 2) void k_gemm(const unsigned short* __restrict__ A,
                                                 const unsigned short* __restrict__ B,
                                                 float* __restrict__ C, const int ldc) {
  __shared__ unsigned short lsA[6][4096];   // [slot][128 rows][32 k] swizzled
  __shared__ unsigned short lsB[6][8192];   // [slot][256 rows][32 k] swizzled
  const int tid = threadIdx.x;
  const int lane = tid & 63;
  const int wave = tid >> 6;
  const int wm = wave >> 2, wn = wave & 3;
  // bijective XCD-aware swizzle (gridDim.x % 8 == 0 for both grids)
  const int bid = blockIdx.x;
  const int swz = (bid & 7) * (gridDim.x >> 3) + (bid >> 3);
  const int t0 = (swz & 31) * 128;   // M = 4096 -> 32 m-tiles always
  const int n0 = (swz >> 5) * 256;
  const unsigned short* Ab = A + (size_t)t0 * DD;
  const unsigned short* Bb = B + (size_t)n0 * DD;
  // staging coords (per thread): row = tid>>2, pre-swizzled k-group
  const int srow = tid >> 2;
  const int scol = ((tid & 3) ^ ((tid >> 3) & 3)) * 8;
  // read coords (per lane)
  const int fr = lane & 15, g = lane >> 4;
  const int xk = (g ^ ((fr >> 1) & 3)) << 3;      // swizzled elem offset in row
  const int arow = (wm * 64 + fr) * 32 + xk;      // + mi*512
  const int brow = (wn * 64 + fr) * 32 + xk;      // + ni*512

#define STAGE(slot, tile)                                                             \
  {                                                                                   \
    const size_t _kb = (size_t)(tile) * 32 + scol;                                    \
    gload_lds16(Ab + (size_t)srow * DD + _kb,         &lsA[slot][tid * 8]);           \
    gload_lds16(Bb + (size_t)srow * DD + _kb,         &lsB[slot][tid * 8]);           \
    gload_lds16(Bb + (size_t)(128 + srow) * DD + _kb, &lsB[slot][4096 + tid * 8]);    \
  }

  f32x4 acc[4][4];
#pragma unroll
  for (int i = 0; i < 4; ++i)
#pragma unroll
    for (int j = 0; j < 4; ++j) acc[i][j] = (f32x4){0.f, 0.f, 0.f, 0.f};

  const int NT = DD / 32;  // 64 K-tiles
  // prologue: stage tiles 0..4 into slots 0..4 (15 loads); wait oldest 3 (tile 0)
  STAGE(0, 0);
  STAGE(1, 1);
  STAGE(2, 2);
  STAGE(3, 3);
  STAGE(4, 4);
  asm volatile("s_waitcnt vmcnt(12)" ::: "memory");
  __builtin_amdgcn_s_barrier();

  int qc = 0;   // current slot  (t % 6)
  int qp = 5;   // prefetch slot ((t+5) % 6)
  for (int t = 0; t < NT; ++t) {
    if (t + 5 < NT) STAGE(qp, t + 5);
    bf16x8 af[4], bg[4];
#pragma unroll
    for (int mi = 0; mi < 4; ++mi) af[mi] = *(const bf16x8*)&lsA[qc][arow + mi * 512];
#pragma unroll
    for (int ni = 0; ni < 4; ++ni) bg[ni] = *(const bf16x8*)&lsB[qc][brow + ni * 512];
    if (t < NT - 5)       asm volatile("s_waitcnt vmcnt(12)" ::: "memory");
    else if (t == NT - 5) asm volatile("s_waitcnt vmcnt(9)" ::: "memory");
    else if (t == NT - 4) asm volatile("s_waitcnt vmcnt(6)" ::: "memory");
    else if (t == NT - 3) asm volatile("s_waitcnt vmcnt(3)" ::: "memory");
    else                  asm volatile("s_waitcnt vmcnt(0)" ::: "memory");
    __builtin_amdgcn_s_barrier();
    __builtin_amdgcn_s_setprio(1);
#pragma unroll
    for (int mi = 0; mi < 4; ++mi)
#pragma unroll
      for (int ni = 0; ni < 4; ++ni)
        acc[mi][ni] = __builtin_amdgcn_mfma_f32_16x16x32_bf16(af[mi], bg[ni],
                                                              acc[mi][ni], 0, 0, 0);
    __builtin_amdgcn_s_setprio(0);
    __builtin_amdgcn_s_barrier();
    qc = (qc == 5) ? 0 : qc + 1;
    qp = (qp == 5) ? 0 : qp + 1;
  }
#undef STAGE

  const int orow = t0 + wm * 64 + g * 4;
  const int ocol = n0 + wn * 64 + fr;
#pragma unroll
  for (int mi = 0; mi < 4; ++mi)
#pragma unroll
    for (int ni = 0; ni < 4; ++ni)
#pragma unroll
      for (int j = 0; j < 4; ++j) {
        const size_t idx = (size_t)(orow + mi * 16 + j) * ldc + (ocol + ni * 16);
        const float v = acc[mi][ni][j];
        if (ACT == 0)      C[idx] += v;
        else if (ACT == 1) C[idx] += v / (1.f + __expf(-v));
        else               C[idx] = v;
      }
}

// ---------------- f32 -> bf16 bulk convert ----------------
__global__ void k_cvt(const float* __restrict__ in, unsigned short* __restrict__ out, int n4) {
  int i = blockIdx.x * blockDim.x + threadIdx.x;
  const int stride = gridDim.x * blockDim.x;
  for (; i < n4; i += stride) {
    const float4 v = ((const float4*)in)[i];
    ushort4 o;
    o.x = f2bf(v.x); o.y = f2bf(v.y); o.z = f2bf(v.z); o.w = f2bf(v.w);
    ((ushort4*)out)[i] = o;
  }
}

extern "C" void kernel_launch(void* const* d_in, const int* in_sizes, int n_in,
                              void* d_out, int out_size, void* d_ws, size_t ws_size,
                              hipStream_t stream) {
  (void)in_sizes; (void)n_in; (void)out_size; (void)ws_size;
  const int* tokens = (const int*)d_in[0];
  const float* hr = (const float*)d_in[1];
  const float* hi = (const float*)d_in[2];
  const float* kar = (const float*)d_in[3];
  const float* kai = (const float*)d_in[4];
  const float* kbr = (const float*)d_in[5];
  const float* kbi = (const float*)d_in[6];
  const float* lscale = (const float*)d_in[7];
  const float* norm_w = (const float*)d_in[8];
  const float* embed = (const float*)d_in[9];
  const float* lm = (const float*)d_in[10];
  const float* fnw = (const float*)d_in[11];
  float* out = (float*)d_out;
  char* ws = (char*)d_ws;

  // ws layout: W bf16 [24][2048][2048] @0 (192 MiB); h bf16 [4096][2048] after.
  // lm_bf16 overlays W (dead after last layer). x (f32) lives in d_out (dead
  // before the final GEMM overwrites all of d_out).
  unsigned short* W = (unsigned short*)ws;
  unsigned short* h = (unsigned short*)(ws + 201326592);
  unsigned short* lmb = W;
  float* x = out;

  k_gather<<<NROWS, 256, 0, stream>>>(tokens, embed, x);
  k_wrec<<<dim3(32, 32), 256, 0, stream>>>(hr, hi, kar, kai, kbr, kbi, lscale, W);
  for (int l = 0; l < 12; ++l) {
    k_rmsnorm<<<NROWS, 256, 0, stream>>>(x, norm_w + (size_t)l * 2 * DD, h);
    k_gemm<0><<<256, 512, 0, stream>>>(h, W + (size_t)(2 * l) * DD * DD, x, DD);
    k_rmsnorm<<<NROWS, 256, 0, stream>>>(x, norm_w + (size_t)l * 2 * DD + DD, h);
    k_gemm<1><<<256, 512, 0, stream>>>(h, W + (size_t)(2 * l + 1) * DD * DD, x, DD);
  }
  k_rmsnorm<<<NROWS, 256, 0, stream>>>(x, fnw, h);
  k_cvt<<<2048, 256, 0, stream>>>(lm, lmb, VOCAB_N * DD / 4);
  k_gemm<2><<<4000, 512, 0, stream>>>(h, lmb, out, VOCAB_N);
}

// Round 5
// 2860.878 us; speedup vs baseline: 1.3097x; 1.3097x over previous
//
#include <hip/hip_runtime.h>
#include <hip/hip_bf16.h>

#define DD 2048
#define NF 24
#define NROWS 4096
#define VOCAB_N 32000
#define EPS_F 1.1920929e-07f

typedef __attribute__((ext_vector_type(8))) __bf16 bf16x8;
typedef __attribute__((ext_vector_type(4))) float f32x4;

__device__ __forceinline__ unsigned short f2bf(float f) {
  union { float f; unsigned int u; } v; v.f = f;
  unsigned int r = v.u + 0x7fffu + ((v.u >> 16) & 1u);  // RNE
  return (unsigned short)(r >> 16);
}

__device__ __forceinline__ void gload_lds16(const void* g, void* l) {
  __builtin_amdgcn_global_load_lds(
      (const __attribute__((address_space(1))) void*)g,
      (__attribute__((address_space(3))) void*)l, 16, 0, 0);
}

// ---------------- embedding gather ----------------
__global__ __launch_bounds__(256) void k_gather(const int* __restrict__ tok,
                                                const float* __restrict__ embed,
                                                float* __restrict__ x) {
  const int row = blockIdx.x;
  const int t = tok[row];
  const float4* s = (const float4*)(embed + (size_t)t * DD);
  float4* d = (float4*)(x + (size_t)row * DD);
  d[threadIdx.x] = s[threadIdx.x];
  d[threadIdx.x + 256] = s[threadIdx.x + 256];
}

// ---------------- W reconstruction via MFMA ----------------
// For each f: P_r[o][i] = sum_{r<16} kar[r][o]kbr[r][i] + kai[r][o]kbi[r][i]
//             P_i[o][i] = sum_{r<16} kai[r][o]kbr[r][i] - kar[r][o]kbi[r][i]
//             W[f][o][i] = bf16( (hr[o][i]*P_r - hi[o][i]*P_i) * scale[f] )
// Packed as K=32 MFMA: A_pr = [kar;kai], A_pi = [kai;-kar], B = [kbr;kbi].
// Block = 256 thr (4 waves), tile 128(o) x 64(i), loop f=0..23 inside.
// Hologram tile lives in registers (loaded once, reused across all 24 f).
__global__ __launch_bounds__(256) void k_wrec(
    const float* __restrict__ hr, const float* __restrict__ hi,
    const float* __restrict__ kar, const float* __restrict__ kai,
    const float* __restrict__ kbr, const float* __restrict__ kbi,
    const float* __restrict__ scale, unsigned short* __restrict__ W) {
  __shared__ float KAR[16][132], KAI[16][132];   // [r][o] row-major (+pad)
  __shared__ float KBR[16][68], KBI[16][68];     // [r][i] row-major (+pad)
  __shared__ unsigned short Wt[128][72];         // output staging (+pad)
  const int tid = threadIdx.x;
  const int lane = tid & 63, w = tid >> 6;
  const int fr = lane & 15, g = lane >> 4;
  const int o0 = blockIdx.x * 128, i0 = blockIdx.y * 64;

  // hologram values for this thread's 32 outputs (fixed across f)
  float hrg[2][4][4], hig[2][4][4];  // [of][jj][fi]
#pragma unroll
  for (int of = 0; of < 2; ++of)
#pragma unroll
    for (int jj = 0; jj < 4; ++jj) {
      const size_t orow = (size_t)(o0 + w * 32 + of * 16 + g * 4 + jj) * DD + i0;
#pragma unroll
      for (int fi = 0; fi < 4; ++fi) {
        hrg[of][jj][fi] = hr[orow + fi * 16 + fr];
        hig[of][jj][fi] = hi[orow + fi * 16 + fr];
      }
    }

  const int sr = tid >> 4;         // staging row 0..15
  const int sca = (tid & 15) * 8;  // A-keys col base
  const int scb = (tid & 15) * 4;  // B-keys col base
  const int rlo = (g & 1) * 8;     // key row base for this lane's k-range

  for (int f = 0; f < NF; ++f) {
    __syncthreads();  // prev f: Wt copy-out + key reads done
    {
      const size_t ga = ((size_t)f * 16 + sr) * DD;
      *(float4*)&KAR[sr][sca]     = *(const float4*)&kar[ga + o0 + sca];
      *(float4*)&KAR[sr][sca + 4] = *(const float4*)&kar[ga + o0 + sca + 4];
      *(float4*)&KAI[sr][sca]     = *(const float4*)&kai[ga + o0 + sca];
      *(float4*)&KAI[sr][sca + 4] = *(const float4*)&kai[ga + o0 + sca + 4];
      *(float4*)&KBR[sr][scb]     = *(const float4*)&kbr[ga + i0 + scb];
      *(float4*)&KBI[sr][scb]     = *(const float4*)&kbi[ga + i0 + scb];
    }
    __syncthreads();
    // fragments: A row = lane&15 (o), k = g*8+j; B row = lane&15 (i), same k
    bf16x8 aPr[2], aPi[2], bF[4];
#pragma unroll
    for (int of = 0; of < 2; ++of) {
      const int oc = w * 32 + of * 16 + fr;
      union { bf16x8 v; unsigned short u[8]; } pu, pv;
#pragma unroll
      for (int j = 0; j < 8; ++j) {
        const float ka = KAR[rlo + j][oc];
        const float kb = KAI[rlo + j][oc];
        pu.u[j] = f2bf((g < 2) ? ka : kb);    // Pr-A: k<16->kar, else kai
        pv.u[j] = f2bf((g < 2) ? kb : -ka);   // Pi-A: k<16->kai, else -kar
      }
      aPr[of] = pu.v; aPi[of] = pv.v;
    }
#pragma unroll
    for (int fi = 0; fi < 4; ++fi) {
      const int ic = fi * 16 + fr;
      union { bf16x8 v; unsigned short u[8]; } pb;
#pragma unroll
      for (int j = 0; j < 8; ++j) {
        const float vr = KBR[rlo + j][ic];
        const float vi = KBI[rlo + j][ic];
        pb.u[j] = f2bf((g < 2) ? vr : vi);    // B: k<16->kbr, else kbi
      }
      bF[fi] = pb.v;
    }
    const float sc = scale[f];
#pragma unroll
    for (int of = 0; of < 2; ++of)
#pragma unroll
      for (int fi = 0; fi < 4; ++fi) {
        const f32x4 z = (f32x4){0.f, 0.f, 0.f, 0.f};
        const f32x4 cr = __builtin_amdgcn_mfma_f32_16x16x32_bf16(aPr[of], bF[fi], z, 0, 0, 0);
        const f32x4 ci = __builtin_amdgcn_mfma_f32_16x16x32_bf16(aPi[of], bF[fi], z, 0, 0, 0);
#pragma unroll
        for (int jj = 0; jj < 4; ++jj) {
          const float wv = (hrg[of][jj][fi] * cr[jj] - hig[of][jj][fi] * ci[jj]) * sc;
          Wt[w * 32 + of * 16 + g * 4 + jj][fi * 16 + fr] = f2bf(wv);
        }
      }
    __syncthreads();
    // coalesced copy Wt -> W[f][o0+r][i0 .. i0+64)
    {
      const int r = tid >> 1, hh = tid & 1;
      unsigned short* dst = W + ((size_t)f * DD + o0 + r) * DD + i0 + hh * 32;
#pragma unroll
      for (int qq = 0; qq < 4; ++qq)
        *(uint4*)(dst + qq * 8) = *(const uint4*)&Wt[r][hh * 32 + qq * 8];
    }
  }
}

// ---------------- rmsnorm ----------------
__global__ __launch_bounds__(256) void k_rmsnorm(const float* __restrict__ x,
                                                 const float* __restrict__ w,
                                                 unsigned short* __restrict__ h) {
  const int row = blockIdx.x, tid = threadIdx.x;
  const float4* xr = (const float4*)(x + (size_t)row * DD);
  const float4 a = xr[tid], b = xr[tid + 256];
  float s = a.x * a.x + a.y * a.y + a.z * a.z + a.w * a.w +
            b.x * b.x + b.y * b.y + b.z * b.z + b.w * b.w;
#pragma unroll
  for (int m = 32; m; m >>= 1) s += __shfl_xor(s, m);
  __shared__ float part[4];
  if ((tid & 63) == 0) part[tid >> 6] = s;
  __syncthreads();
  const float inv = rsqrtf((part[0] + part[1] + part[2] + part[3]) * (1.f / DD) + EPS_F);
  const float4* wr = (const float4*)w;
  const float4 w0 = wr[tid], w1 = wr[tid + 256];
  ushort4 o0, o1;
  o0.x = f2bf(a.x * inv * w0.x); o0.y = f2bf(a.y * inv * w0.y);
  o0.z = f2bf(a.z * inv * w0.z); o0.w = f2bf(a.w * inv * w0.w);
  o1.x = f2bf(b.x * inv * w1.x); o1.y = f2bf(b.y * inv * w1.y);
  o1.z = f2bf(b.z * inv * w1.z); o1.w = f2bf(b.w * inv * w1.w);
  ushort4* hd = (ushort4*)(h + (size_t)row * DD);
  hd[tid] = o0;
  hd[tid + 256] = o1;
}

// ---------------- GEMM (r1 structure + XOR swizzle) ----------------
// out[t][n] (+)= act( sum_k A[t][k]*B[n][k] ); 128x128 tile, BK=32, 4 waves.
// Swizzle: LDS k-group p holds global k-group p ^ ((row>>1)&3); pre-swizzled
// global source (linear gload_lds dest) + swizzled ds_read addr -> 0 conflicts.
// ACT: 0 = C += v (residual), 1 = C += silu(v), 2 = C = v (store)
template <int ACT>
__global__ __launch_bounds__(256) void k_gemm(const unsigned short* __restrict__ A,
                                              const unsigned short* __restrict__ B,
                                              float* __restrict__ C, int ldc) {
  __shared__ unsigned short lsA[2][4096];
  __shared__ unsigned short lsB[2][4096];
  const int tid = threadIdx.x;
  const int lane = tid & 63, wave = tid >> 6;
  const int wm = wave >> 1, wn = wave & 1;
  const int t0 = blockIdx.x * 128, n0 = blockIdx.y * 128;
  const unsigned short* Ab = A + (size_t)t0 * DD;
  const unsigned short* Bb = B + (size_t)n0 * DD;
  const int srow = tid >> 2;
  const int scol = ((tid & 3) ^ ((tid >> 3) & 3)) * 8;  // pre-swizzled source k-group

  f32x4 acc[4][4];
#pragma unroll
  for (int i = 0; i < 4; ++i)
#pragma unroll
    for (int j = 0; j < 4; ++j) acc[i][j] = (f32x4){0.f, 0.f, 0.f, 0.f};

  const int fr = lane & 15, g = lane >> 4;
  const int xk = (g ^ ((fr >> 1) & 3)) * 8;             // swizzled read k-offset
  const int aoff = (wm * 64 + fr) * 32 + xk;
  const int boff = (wn * 64 + fr) * 32 + xk;

#define STAGE(buf, kt)                                                              \
  {                                                                                 \
    const int kb = (kt) * 32 + scol;                                                \
    gload_lds16(Ab + (size_t)srow * DD + kb,        &lsA[buf][tid * 8]);            \
    gload_lds16(Ab + (size_t)(srow + 64) * DD + kb, &lsA[buf][2048 + tid * 8]);     \
    gload_lds16(Bb + (size_t)srow * DD + kb,        &lsB[buf][tid * 8]);            \
    gload_lds16(Bb + (size_t)(srow + 64) * DD + kb, &lsB[buf][2048 + tid * 8]);     \
  }

  STAGE(0, 0);
  __syncthreads();
  for (int kt = 0; kt < 64; ++kt) {
    const int cur = kt & 1;
    if (kt < 63) STAGE(cur ^ 1, kt + 1);
    bf16x8 af[4], bg[4];
#pragma unroll
    for (int i = 0; i < 4; ++i) {
      af[i] = *(const bf16x8*)&lsA[cur][aoff + i * 16 * 32];
      bg[i] = *(const bf16x8*)&lsB[cur][boff + i * 16 * 32];
    }
#pragma unroll
    for (int mi = 0; mi < 4; ++mi)
#pragma unroll
      for (int ni = 0; ni < 4; ++ni)
        acc[mi][ni] = __builtin_amdgcn_mfma_f32_16x16x32_bf16(af[mi], bg[ni],
                                                              acc[mi][ni], 0, 0, 0);
    __syncthreads();
  }
#undef STAGE

  const int orow = t0 + wm * 64 + g * 4;
  const int ocol = n0 + wn * 64 + fr;
#pragma unroll
  for (int mi = 0; mi < 4; ++mi)
#pragma unroll
    for (int ni = 0; ni < 4; ++ni)
#pragma unroll
      for (int j = 0; j < 4; ++j) {
        const size_t idx = (size_t)(orow + mi * 16 + j) * ldc + (ocol + ni * 16);
        const float v = acc[mi][ni][j];
        if (ACT == 0)      C[idx] += v;
        else if (ACT == 1) C[idx] += v / (1.f + __expf(-v));
        else               C[idx] = v;
      }
}

// ---------------- f32 -> bf16 bulk convert ----------------
__global__ void k_cvt(const float* __restrict__ in, unsigned short* __restrict__ out, int n4) {
  int i = blockIdx.x * blockDim.x + threadIdx.x;
  const int stride = gridDim.x * blockDim.x;
  for (; i < n4; i += stride) {
    const float4 v = ((const float4*)in)[i];
    ushort4 o;
    o.x = f2bf(v.x); o.y = f2bf(v.y); o.z = f2bf(v.z); o.w = f2bf(v.w);
    ((ushort4*)out)[i] = o;
  }
}

extern "C" void kernel_launch(void* const* d_in, const int* in_sizes, int n_in,
                              void* d_out, int out_size, void* d_ws, size_t ws_size,
                              hipStream_t stream) {
  (void)in_sizes; (void)n_in; (void)out_size; (void)ws_size;
  const int* tokens = (const int*)d_in[0];
  const float* hr = (const float*)d_in[1];
  const float* hi = (const float*)d_in[2];
  const float* kar = (const float*)d_in[3];
  const float* kai = (const float*)d_in[4];
  const float* kbr = (const float*)d_in[5];
  const float* kbi = (const float*)d_in[6];
  const float* lscale = (const float*)d_in[7];
  const float* norm_w = (const float*)d_in[8];
  const float* embed = (const float*)d_in[9];
  const float* lm = (const float*)d_in[10];
  const float* fnw = (const float*)d_in[11];
  float* out = (float*)d_out;
  char* ws = (char*)d_ws;

  // ws layout: W bf16 [24][2048][2048] @0 (192 MiB); h bf16 [4096][2048] after.
  // lm_bf16 overlays W (dead after last layer). x (f32) lives in d_out (dead
  // before the final GEMM overwrites all of d_out).
  unsigned short* W = (unsigned short*)ws;
  unsigned short* h = (unsigned short*)(ws + 201326592);
  unsigned short* lmb = W;
  float* x = out;

  k_gather<<<NROWS, 256, 0, stream>>>(tokens, embed, x);
  k_wrec<<<dim3(16, 32), 256, 0, stream>>>(hr, hi, kar, kai, kbr, kbi, lscale, W);
  for (int l = 0; l < 12; ++l) {
    k_rmsnorm<<<NROWS, 256, 0, stream>>>(x, norm_w + (size_t)l * 2 * DD, h);
    k_gemm<0><<<dim3(32, 16), 256, 0, stream>>>(h, W + (size_t)(2 * l) * DD * DD, x, DD);
    k_rmsnorm<<<NROWS, 256, 0, stream>>>(x, norm_w + (size_t)l * 2 * DD + DD, h);
    k_gemm<1><<<dim3(32, 16), 256, 0, stream>>>(h, W + (size_t)(2 * l + 1) * DD * DD, x, DD);
  }
  k_rmsnorm<<<NROWS, 256, 0, stream>>>(x, fnw, h);
  k_cvt<<<2048, 256, 0, stream>>>(lm, lmb, VOCAB_N * DD / 4);
  k_gemm<2><<<dim3(32, 250), 256, 0, stream>>>(h, lmb, out, VOCAB_N);
}

// Round 6
// 2475.850 us; speedup vs baseline: 1.5134x; 1.1555x over previous
//
#include <hip/hip_runtime.h>
#include <hip/hip_bf16.h>

#define DD 2048
#define NF 24
#define NROWS 4096
#define VOCAB_N 32000
#define EPS_F 1.1920929e-07f

typedef __attribute__((ext_vector_type(8))) __bf16 bf16x8;
typedef __attribute__((ext_vector_type(4))) float f32x4;

__device__ __forceinline__ unsigned short f2bf(float f) {
  union { float f; unsigned int u; } v; v.f = f;
  unsigned int r = v.u + 0x7fffu + ((v.u >> 16) & 1u);  // RNE
  return (unsigned short)(r >> 16);
}

__device__ __forceinline__ void gload_lds16(const void* g, void* l) {
  __builtin_amdgcn_global_load_lds(
      (const __attribute__((address_space(1))) void*)g,
      (__attribute__((address_space(3))) void*)l, 16, 0, 0);
}

// ---------------- embedding gather ----------------
__global__ __launch_bounds__(256) void k_gather(const int* __restrict__ tok,
                                                const float* __restrict__ embed,
                                                float* __restrict__ x) {
  const int row = blockIdx.x;
  const int t = tok[row];
  const float4* s = (const float4*)(embed + (size_t)t * DD);
  float4* d = (float4*)(x + (size_t)row * DD);
  d[threadIdx.x] = s[threadIdx.x];
  d[threadIdx.x + 256] = s[threadIdx.x + 256];
}

// ---------------- W reconstruction via MFMA (r5, unchanged) ----------------
__global__ __launch_bounds__(256) void k_wrec(
    const float* __restrict__ hr, const float* __restrict__ hi,
    const float* __restrict__ kar, const float* __restrict__ kai,
    const float* __restrict__ kbr, const float* __restrict__ kbi,
    const float* __restrict__ scale, unsigned short* __restrict__ W) {
  __shared__ float KAR[16][132], KAI[16][132];
  __shared__ float KBR[16][68], KBI[16][68];
  __shared__ unsigned short Wt[128][72];
  const int tid = threadIdx.x;
  const int lane = tid & 63, w = tid >> 6;
  const int fr = lane & 15, g = lane >> 4;
  const int o0 = blockIdx.x * 128, i0 = blockIdx.y * 64;

  float hrg[2][4][4], hig[2][4][4];
#pragma unroll
  for (int of = 0; of < 2; ++of)
#pragma unroll
    for (int jj = 0; jj < 4; ++jj) {
      const size_t orow = (size_t)(o0 + w * 32 + of * 16 + g * 4 + jj) * DD + i0;
#pragma unroll
      for (int fi = 0; fi < 4; ++fi) {
        hrg[of][jj][fi] = hr[orow + fi * 16 + fr];
        hig[of][jj][fi] = hi[orow + fi * 16 + fr];
      }
    }

  const int sr = tid >> 4;
  const int sca = (tid & 15) * 8;
  const int scb = (tid & 15) * 4;
  const int rlo = (g & 1) * 8;

  for (int f = 0; f < NF; ++f) {
    __syncthreads();
    {
      const size_t ga = ((size_t)f * 16 + sr) * DD;
      *(float4*)&KAR[sr][sca]     = *(const float4*)&kar[ga + o0 + sca];
      *(float4*)&KAR[sr][sca + 4] = *(const float4*)&kar[ga + o0 + sca + 4];
      *(float4*)&KAI[sr][sca]     = *(const float4*)&kai[ga + o0 + sca];
      *(float4*)&KAI[sr][sca + 4] = *(const float4*)&kai[ga + o0 + sca + 4];
      *(float4*)&KBR[sr][scb]     = *(const float4*)&kbr[ga + i0 + scb];
      *(float4*)&KBI[sr][scb]     = *(const float4*)&kbi[ga + i0 + scb];
    }
    __syncthreads();
    bf16x8 aPr[2], aPi[2], bF[4];
#pragma unroll
    for (int of = 0; of < 2; ++of) {
      const int oc = w * 32 + of * 16 + fr;
      union { bf16x8 v; unsigned short u[8]; } pu, pv;
#pragma unroll
      for (int j = 0; j < 8; ++j) {
        const float ka = KAR[rlo + j][oc];
        const float kb = KAI[rlo + j][oc];
        pu.u[j] = f2bf((g < 2) ? ka : kb);
        pv.u[j] = f2bf((g < 2) ? kb : -ka);
      }
      aPr[of] = pu.v; aPi[of] = pv.v;
    }
#pragma unroll
    for (int fi = 0; fi < 4; ++fi) {
      const int ic = fi * 16 + fr;
      union { bf16x8 v; unsigned short u[8]; } pb;
#pragma unroll
      for (int j = 0; j < 8; ++j) {
        const float vr = KBR[rlo + j][ic];
        const float vi = KBI[rlo + j][ic];
        pb.u[j] = f2bf((g < 2) ? vr : vi);
      }
      bF[fi] = pb.v;
    }
    const float sc = scale[f];
#pragma unroll
    for (int of = 0; of < 2; ++of)
#pragma unroll
      for (int fi = 0; fi < 4; ++fi) {
        const f32x4 z = (f32x4){0.f, 0.f, 0.f, 0.f};
        const f32x4 cr = __builtin_amdgcn_mfma_f32_16x16x32_bf16(aPr[of], bF[fi], z, 0, 0, 0);
        const f32x4 ci = __builtin_amdgcn_mfma_f32_16x16x32_bf16(aPi[of], bF[fi], z, 0, 0, 0);
#pragma unroll
        for (int jj = 0; jj < 4; ++jj) {
          const float wv = (hrg[of][jj][fi] * cr[jj] - hig[of][jj][fi] * ci[jj]) * sc;
          Wt[w * 32 + of * 16 + g * 4 + jj][fi * 16 + fr] = f2bf(wv);
        }
      }
    __syncthreads();
    {
      const int r = tid >> 1, hh = tid & 1;
      unsigned short* dst = W + ((size_t)f * DD + o0 + r) * DD + i0 + hh * 32;
#pragma unroll
      for (int qq = 0; qq < 4; ++qq)
        *(uint4*)(dst + qq * 8) = *(const uint4*)&Wt[r][hh * 32 + qq * 8];
    }
  }
}

// ---------------- rmsnorm ----------------
__global__ __launch_bounds__(256) void k_rmsnorm(const float* __restrict__ x,
                                                 const float* __restrict__ w,
                                                 unsigned short* __restrict__ h) {
  const int row = blockIdx.x, tid = threadIdx.x;
  const float4* xr = (const float4*)(x + (size_t)row * DD);
  const float4 a = xr[tid], b = xr[tid + 256];
  float s = a.x * a.x + a.y * a.y + a.z * a.z + a.w * a.w +
            b.x * b.x + b.y * b.y + b.z * b.z + b.w * b.w;
#pragma unroll
  for (int m = 32; m; m >>= 1) s += __shfl_xor(s, m);
  __shared__ float part[4];
  if ((tid & 63) == 0) part[tid >> 6] = s;
  __syncthreads();
  const float inv = rsqrtf((part[0] + part[1] + part[2] + part[3]) * (1.f / DD) + EPS_F);
  const float4* wr = (const float4*)w;
  const float4 w0 = wr[tid], w1 = wr[tid + 256];
  ushort4 o0, o1;
  o0.x = f2bf(a.x * inv * w0.x); o0.y = f2bf(a.y * inv * w0.y);
  o0.z = f2bf(a.z * inv * w0.z); o0.w = f2bf(a.w * inv * w0.w);
  o1.x = f2bf(b.x * inv * w1.x); o1.y = f2bf(b.y * inv * w1.y);
  o1.z = f2bf(b.z * inv * w1.z); o1.w = f2bf(b.w * inv * w1.w);
  ushort4* hd = (ushort4*)(h + (size_t)row * DD);
  hd[tid] = o0;
  hd[tid + 256] = o1;
}

// ---------------- 8-phase GEMM (m201-template port) ----------------
// out[t][n] (+)= act( sum_k A[t][k]*B[n][k] );  A:[M][2048], B:[N][2048] bf16.
// BN=256, BK=64, 8 waves (2M x 4N); BM=256 (per-wave 128x64) or BM=128 (64x64).
// Double-buffer: even K-tiles -> buf0, odd -> buf1.  Per iteration (2 K-tiles),
// 8 phases; phase = { ds-read quadrant frags | stage 1 half-tile | [vmcnt@ph3/7]
// | barrier | lgkmcnt(0) | setprio(1) MFMA quadrant setprio(0) | barrier }.
// Quadrant zigzag (mh,nh): (0,0)(0,1)(1,1)(1,0) keeps A-quad and both-B-halves
// in regs (loads per phase: A+B, B, A, none).  Stage map (iter i, steady):
//   ph0:A(2i+1)h1  ph1:B(2i+1)h1  ph2:B(2i+2)h0  ph3:A(2i+2)h0
//   ph4:A(2i+2)h1  ph5:B(2i+2)h1  ph6:B(2i+3)h0  ph7:A(2i+3)h0
// Each stage targets a region whose reads finished >=1 barrier earlier.
// vmcnt(2+A_LOADS) at ph3/ph7 leaves only the last 2 half-tiles in flight =>
// tile 2i+1 landed before ph4, tile 2i+2 before next ph0.  Last iter: vmcnt(0)
// at ph3 (no ph2/3 stages to push ph0/1 out of the window).
// LDS XOR-swizzle: k-slot s at row r holds global slot s^(r&7); applied on the
// pre-swizzled global source (linear gload_lds dest) and on ds_read addrs.
// ACT: 0 = C += v, 1 = C += silu(v), 2 = C = v
template <int ACT, int BM>
__global__ __launch_bounds__(512, 2) void k_gemm8(const unsigned short* __restrict__ A,
                                                  const unsigned short* __restrict__ B,
                                                  float* __restrict__ C, const int ldc,
                                                  const int mtiles) {
  constexpr int HALF = BM / 2;          // rows per A half-tile
  constexpr int MI = BM / 32;           // mi frags per wave (8 or 4)
  constexpr int MQ = MI / 2;            // mi per quadrant
  constexpr int A_LOADS = HALF / 64;    // gloads per A half (2 or 1)
  constexpr int NTILE = DD / 64;        // 32 K-tiles
  constexpr int NITER = NTILE / 2;      // 16

  __shared__ unsigned short lsA[2][BM * 64];
  __shared__ unsigned short lsB[2][256 * 64];

  const int tid = threadIdx.x;
  const int lane = tid & 63, wave = tid >> 6;
  const int wm = wave >> 2, wn = wave & 3;
  const int bid = blockIdx.x;
  const int swz = (bid & 7) * (gridDim.x >> 3) + (bid >> 3);
  const int t0 = (swz % mtiles) * BM;
  const int n0 = (swz / mtiles) * 256;
  const unsigned short* Ab = A + (size_t)t0 * DD;
  const unsigned short* Bb = B + (size_t)n0 * DD;
  const int fr = lane & 15, g = lane >> 4;
  const int srow8 = tid >> 3, sslot = tid & 7;

#define STG_A(buf, h, tile)                                                         \
  { _Pragma("unroll")                                                               \
    for (int l = 0; l < A_LOADS; ++l) {                                             \
      const int rt = (h) * HALF + l * 64 + srow8;                                   \
      gload_lds16(Ab + (size_t)rt * DD + (tile) * 64 + ((sslot ^ (rt & 7)) << 3),   \
                  &lsA[buf][rt * 64 + sslot * 8]);                                  \
    } }
#define STG_B(buf, h, tile)                                                         \
  { _Pragma("unroll")                                                               \
    for (int l = 0; l < 2; ++l) {                                                   \
      const int rt = (h) * 128 + l * 64 + srow8;                                    \
      gload_lds16(Bb + (size_t)rt * DD + (tile) * 64 + ((sslot ^ (rt & 7)) << 3),   \
                  &lsB[buf][rt * 64 + sslot * 8]);                                  \
    } }
#define VM_STEADY()                                                                 \
  { if constexpr (BM == 256) asm volatile("s_waitcnt vmcnt(4)" ::: "memory");       \
    else                     asm volatile("s_waitcnt vmcnt(3)" ::: "memory"); }
#define VM_ZERO() asm volatile("s_waitcnt vmcnt(0)" ::: "memory")

  f32x4 acc[MI][4];
#pragma unroll
  for (int i = 0; i < MI; ++i)
#pragma unroll
    for (int j = 0; j < 4; ++j) acc[i][j] = (f32x4){0.f, 0.f, 0.f, 0.f};

  bf16x8 aF[MQ][2];      // current A quadrant [mi_local][ks]
  bf16x8 bF[2][2][2];    // both B halves [nh][ni_local][ks]

#define RD_A(buf, mi, ks)                                                           \
  (*(const bf16x8*)&lsA[buf][(wm * HALF + (mi) * 16 + fr) * 64 +                    \
                             ((((ks) * 4 + g) ^ ((wm * HALF + (mi) * 16 + fr) & 7)) << 3)])
#define RD_B(buf, ni, ks)                                                           \
  (*(const bf16x8*)&lsB[buf][(wn * 64 + (ni) * 16 + fr) * 64 +                      \
                             ((((ks) * 4 + g) ^ ((wn * 64 + (ni) * 16 + fr) & 7)) << 3)])

#define PHASE(buf, mh, nh, LA, LB, STAGES, VMK)                                     \
  {                                                                                 \
    if (LA) { _Pragma("unroll")                                                     \
      for (int q = 0; q < MQ; ++q) { _Pragma("unroll")                              \
        for (int ks = 0; ks < 2; ++ks) aF[q][ks] = RD_A(buf, (mh) * MQ + q, ks); } }\
    if (LB) { _Pragma("unroll")                                                     \
      for (int q = 0; q < 2; ++q) { _Pragma("unroll")                               \
        for (int ks = 0; ks < 2; ++ks) bF[nh][q][ks] = RD_B(buf, (nh) * 2 + q, ks); } } \
    STAGES;                                                                         \
    VMK;                                                                            \
    __builtin_amdgcn_s_barrier();                                                   \
    asm volatile("s_waitcnt lgkmcnt(0)" ::: "memory");                              \
    __builtin_amdgcn_s_setprio(1);                                                  \
    _Pragma("unroll")                                                               \
    for (int ks = 0; ks < 2; ++ks) { _Pragma("unroll")                              \
      for (int q = 0; q < MQ; ++q) { _Pragma("unroll")                              \
        for (int nq = 0; nq < 2; ++nq)                                              \
          acc[(mh) * MQ + q][(nh) * 2 + nq] = __builtin_amdgcn_mfma_f32_16x16x32_bf16( \
              aF[q][ks], bF[nh][nq][ks], acc[(mh) * MQ + q][(nh) * 2 + nq], 0, 0, 0); } } \
    __builtin_amdgcn_s_setprio(0);                                                  \
    __builtin_amdgcn_s_barrier();                                                   \
  }

  // prologue: tiles 0 (buf0) and 1 (buf1) fully staged, full drain
  STG_A(0, 0, 0); STG_A(0, 1, 0); STG_B(0, 0, 0); STG_B(0, 1, 0);
  STG_A(1, 0, 1); STG_A(1, 1, 1); STG_B(1, 0, 1); STG_B(1, 1, 1);
  VM_ZERO();
  __builtin_amdgcn_s_barrier();

  for (int i = 0; i < NITER; ++i) {
    const int T1 = 2 * i + 1, T2 = 2 * i + 2, T3 = 2 * i + 3;
    const bool s2 = T2 < NTILE, s3 = T3 < NTILE;
    PHASE(0, 0, 0, true,  true,  { if (i > 0) STG_A(1, 1, T1); }, {});
    PHASE(0, 0, 1, false, true,  { if (i > 0) STG_B(1, 1, T1); }, {});
    PHASE(0, 1, 1, true,  false, { if (s2) STG_B(0, 0, T2); },    {});
    PHASE(0, 1, 0, false, false, { if (s2) STG_A(0, 0, T2); },
          { if (s2) VM_STEADY() else VM_ZERO(); });
    PHASE(1, 0, 0, true,  true,  { if (s2) STG_A(0, 1, T2); },    {});
    PHASE(1, 0, 1, false, true,  { if (s2) STG_B(0, 1, T2); },    {});
    PHASE(1, 1, 1, true,  false, { if (s3) STG_B(1, 0, T3); },    {});
    PHASE(1, 1, 0, false, false, { if (s3) STG_A(1, 0, T3); },
          { if (s3) VM_STEADY() else VM_ZERO(); });
  }
#undef PHASE
#undef RD_A
#undef RD_B
#undef STG_A
#undef STG_B
#undef VM_STEADY
#undef VM_ZERO

  // epilogue
#pragma unroll
  for (int mi = 0; mi < MI; ++mi) {
    const int orow = t0 + wm * HALF + mi * 16 + g * 4;
#pragma unroll
    for (int ni = 0; ni < 4; ++ni) {
      const int ocol = n0 + wn * 64 + ni * 16 + fr;
#pragma unroll
      for (int j = 0; j < 4; ++j) {
        const size_t idx = (size_t)(orow + j) * ldc + ocol;
        const float v = acc[mi][ni][j];
        if (ACT == 0)      C[idx] += v;
        else if (ACT == 1) C[idx] += v / (1.f + __expf(-v));
        else               C[idx] = v;
      }
    }
  }
}

// ---------------- f32 -> bf16 bulk convert ----------------
__global__ void k_cvt(const float* __restrict__ in, unsigned short* __restrict__ out, int n4) {
  int i = blockIdx.x * blockDim.x + threadIdx.x;
  const int stride = gridDim.x * blockDim.x;
  for (; i < n4; i += stride) {
    const float4 v = ((const float4*)in)[i];
    ushort4 o;
    o.x = f2bf(v.x); o.y = f2bf(v.y); o.z = f2bf(v.z); o.w = f2bf(v.w);
    ((ushort4*)out)[i] = o;
  }
}

extern "C" void kernel_launch(void* const* d_in, const int* in_sizes, int n_in,
                              void* d_out, int out_size, void* d_ws, size_t ws_size,
                              hipStream_t stream) {
  (void)in_sizes; (void)n_in; (void)out_size; (void)ws_size;
  const int* tokens = (const int*)d_in[0];
  const float* hr = (const float*)d_in[1];
  const float* hi = (const float*)d_in[2];
  const float* kar = (const float*)d_in[3];
  const float* kai = (const float*)d_in[4];
  const float* kbr = (const float*)d_in[5];
  const float* kbi = (const float*)d_in[6];
  const float* lscale = (const float*)d_in[7];
  const float* norm_w = (const float*)d_in[8];
  const float* embed = (const float*)d_in[9];
  const float* lm = (const float*)d_in[10];
  const float* fnw = (const float*)d_in[11];
  float* out = (float*)d_out;
  char* ws = (char*)d_ws;

  // ws layout: W bf16 [24][2048][2048] @0 (192 MiB); h bf16 [4096][2048] after.
  // lm_bf16 overlays W (dead after last layer). x (f32) lives in d_out (dead
  // before the final GEMM overwrites all of d_out).
  unsigned short* W = (unsigned short*)ws;
  unsigned short* h = (unsigned short*)(ws + 201326592);
  unsigned short* lmb = W;
  float* x = out;

  k_gather<<<NROWS, 256, 0, stream>>>(tokens, embed, x);
  k_wrec<<<dim3(16, 32), 256, 0, stream>>>(hr, hi, kar, kai, kbr, kbi, lscale, W);
  for (int l = 0; l < 12; ++l) {
    k_rmsnorm<<<NROWS, 256, 0, stream>>>(x, norm_w + (size_t)l * 2 * DD, h);
    k_gemm8<0, 128><<<256, 512, 0, stream>>>(h, W + (size_t)(2 * l) * DD * DD, x, DD, 32);
    k_rmsnorm<<<NROWS, 256, 0, stream>>>(x, norm_w + (size_t)l * 2 * DD + DD, h);
    k_gemm8<1, 128><<<256, 512, 0, stream>>>(h, W + (size_t)(2 * l + 1) * DD * DD, x, DD, 32);
  }
  k_rmsnorm<<<NROWS, 256, 0, stream>>>(x, fnw, h);
  k_cvt<<<2048, 256, 0, stream>>>(lm, lmb, VOCAB_N * DD / 4);
  k_gemm8<2, 256><<<2000, 512, 0, stream>>>(h, lmb, out, VOCAB_N, 16);
}

// Round 7
// 2344.821 us; speedup vs baseline: 1.5979x; 1.0559x over previous
//
#include <hip/hip_runtime.h>
#include <hip/hip_bf16.h>

#define DD 2048
#define NF 24
#define NROWS 4096
#define VOCAB_N 32000
#define EPS_F 1.1920929e-07f

typedef __attribute__((ext_vector_type(8))) __bf16 bf16x8;
typedef __attribute__((ext_vector_type(4))) float f32x4;

__device__ __forceinline__ unsigned short f2bf(float f) {
  union { float f; unsigned int u; } v; v.f = f;
  unsigned int r = v.u + 0x7fffu + ((v.u >> 16) & 1u);  // RNE
  return (unsigned short)(r >> 16);
}

__device__ __forceinline__ void gload_lds16(const void* g, void* l) {
  __builtin_amdgcn_global_load_lds(
      (const __attribute__((address_space(1))) void*)g,
      (__attribute__((address_space(3))) void*)l, 16, 0, 0);
}

// ---------------- embedding gather ----------------
__global__ __launch_bounds__(256) void k_gather(const int* __restrict__ tok,
                                                const float* __restrict__ embed,
                                                float* __restrict__ x) {
  const int row = blockIdx.x;
  const int t = tok[row];
  const float4* s = (const float4*)(embed + (size_t)t * DD);
  float4* d = (float4*)(x + (size_t)row * DD);
  d[threadIdx.x] = s[threadIdx.x];
  d[threadIdx.x + 256] = s[threadIdx.x + 256];
}

// ---------------- W reconstruction via MFMA (r5, unchanged) ----------------
__global__ __launch_bounds__(256) void k_wrec(
    const float* __restrict__ hr, const float* __restrict__ hi,
    const float* __restrict__ kar, const float* __restrict__ kai,
    const float* __restrict__ kbr, const float* __restrict__ kbi,
    const float* __restrict__ scale, unsigned short* __restrict__ W) {
  __shared__ float KAR[16][132], KAI[16][132];
  __shared__ float KBR[16][68], KBI[16][68];
  __shared__ unsigned short Wt[128][72];
  const int tid = threadIdx.x;
  const int lane = tid & 63, w = tid >> 6;
  const int fr = lane & 15, g = lane >> 4;
  const int o0 = blockIdx.x * 128, i0 = blockIdx.y * 64;

  float hrg[2][4][4], hig[2][4][4];
#pragma unroll
  for (int of = 0; of < 2; ++of)
#pragma unroll
    for (int jj = 0; jj < 4; ++jj) {
      const size_t orow = (size_t)(o0 + w * 32 + of * 16 + g * 4 + jj) * DD + i0;
#pragma unroll
      for (int fi = 0; fi < 4; ++fi) {
        hrg[of][jj][fi] = hr[orow + fi * 16 + fr];
        hig[of][jj][fi] = hi[orow + fi * 16 + fr];
      }
    }

  const int sr = tid >> 4;
  const int sca = (tid & 15) * 8;
  const int scb = (tid & 15) * 4;
  const int rlo = (g & 1) * 8;

  for (int f = 0; f < NF; ++f) {
    __syncthreads();
    {
      const size_t ga = ((size_t)f * 16 + sr) * DD;
      *(float4*)&KAR[sr][sca]     = *(const float4*)&kar[ga + o0 + sca];
      *(float4*)&KAR[sr][sca + 4] = *(const float4*)&kar[ga + o0 + sca + 4];
      *(float4*)&KAI[sr][sca]     = *(const float4*)&kai[ga + o0 + sca];
      *(float4*)&KAI[sr][sca + 4] = *(const float4*)&kai[ga + o0 + sca + 4];
      *(float4*)&KBR[sr][scb]     = *(const float4*)&kbr[ga + i0 + scb];
      *(float4*)&KBI[sr][scb]     = *(const float4*)&kbi[ga + i0 + scb];
    }
    __syncthreads();
    bf16x8 aPr[2], aPi[2], bF[4];
#pragma unroll
    for (int of = 0; of < 2; ++of) {
      const int oc = w * 32 + of * 16 + fr;
      union { bf16x8 v; unsigned short u[8]; } pu, pv;
#pragma unroll
      for (int j = 0; j < 8; ++j) {
        const float ka = KAR[rlo + j][oc];
        const float kb = KAI[rlo + j][oc];
        pu.u[j] = f2bf((g < 2) ? ka : kb);
        pv.u[j] = f2bf((g < 2) ? kb : -ka);
      }
      aPr[of] = pu.v; aPi[of] = pv.v;
    }
#pragma unroll
    for (int fi = 0; fi < 4; ++fi) {
      const int ic = fi * 16 + fr;
      union { bf16x8 v; unsigned short u[8]; } pb;
#pragma unroll
      for (int j = 0; j < 8; ++j) {
        const float vr = KBR[rlo + j][ic];
        const float vi = KBI[rlo + j][ic];
        pb.u[j] = f2bf((g < 2) ? vr : vi);
      }
      bF[fi] = pb.v;
    }
    const float sc = scale[f];
#pragma unroll
    for (int of = 0; of < 2; ++of)
#pragma unroll
      for (int fi = 0; fi < 4; ++fi) {
        const f32x4 z = (f32x4){0.f, 0.f, 0.f, 0.f};
        const f32x4 cr = __builtin_amdgcn_mfma_f32_16x16x32_bf16(aPr[of], bF[fi], z, 0, 0, 0);
        const f32x4 ci = __builtin_amdgcn_mfma_f32_16x16x32_bf16(aPi[of], bF[fi], z, 0, 0, 0);
#pragma unroll
        for (int jj = 0; jj < 4; ++jj) {
          const float wv = (hrg[of][jj][fi] * cr[jj] - hig[of][jj][fi] * ci[jj]) * sc;
          Wt[w * 32 + of * 16 + g * 4 + jj][fi * 16 + fr] = f2bf(wv);
        }
      }
    __syncthreads();
    {
      const int r = tid >> 1, hh = tid & 1;
      unsigned short* dst = W + ((size_t)f * DD + o0 + r) * DD + i0 + hh * 32;
#pragma unroll
      for (int qq = 0; qq < 4; ++qq)
        *(uint4*)(dst + qq * 8) = *(const uint4*)&Wt[r][hh * 32 + qq * 8];
    }
  }
}

// ---------------- rmsnorm ----------------
__global__ __launch_bounds__(256) void k_rmsnorm(const float* __restrict__ x,
                                                 const float* __restrict__ w,
                                                 unsigned short* __restrict__ h) {
  const int row = blockIdx.x, tid = threadIdx.x;
  const float4* xr = (const float4*)(x + (size_t)row * DD);
  const float4 a = xr[tid], b = xr[tid + 256];
  float s = a.x * a.x + a.y * a.y + a.z * a.z + a.w * a.w +
            b.x * b.x + b.y * b.y + b.z * b.z + b.w * b.w;
#pragma unroll
  for (int m = 32; m; m >>= 1) s += __shfl_xor(s, m);
  __shared__ float part[4];
  if ((tid & 63) == 0) part[tid >> 6] = s;
  __syncthreads();
  const float inv = rsqrtf((part[0] + part[1] + part[2] + part[3]) * (1.f / DD) + EPS_F);
  const float4* wr = (const float4*)w;
  const float4 w0 = wr[tid], w1 = wr[tid + 256];
  ushort4 o0, o1;
  o0.x = f2bf(a.x * inv * w0.x); o0.y = f2bf(a.y * inv * w0.y);
  o0.z = f2bf(a.z * inv * w0.z); o0.w = f2bf(a.w * inv * w0.w);
  o1.x = f2bf(b.x * inv * w1.x); o1.y = f2bf(b.y * inv * w1.y);
  o1.z = f2bf(b.z * inv * w1.z); o1.w = f2bf(b.w * inv * w1.w);
  ushort4* hd = (ushort4*)(h + (size_t)row * DD);
  hd[tid] = o0;
  hd[tid + 256] = o1;
}

// ---------------- 8-phase GEMM, lead-corrected stage map ----------------
// out[t][n] (+)= act( sum_k A[t][k]*B[n][k] );  A:[M][2048], B:[N][2048] bf16.
// BN=256, BK=64, 8 waves (2M x 4N); BM=256 (per-wave 128x64) or BM=128 (64x64).
// Even K-tiles -> buf0 (phases 0-3), odd -> buf1 (phases 4-7). Quadrant zigzag
// (mh,nh) = (0,0)(0,1)(1,1)(1,0): LDS reads per phase: A+B / B / A / none —
// so B(bufX) is ds_read-free after its nh1 phase, A(bufX) after its mh1 phase.
// Region-free-derived stage map (all leads 3-5 phases; stall ~= max(0,900-750)):
//   ph2: B(t+2) h0+h1 -> buf0      ph6: B(t+3) h0+h1 -> buf1
//   ph3: A(t+2) h0    -> buf0      ph7: A(t+3) h0+h1 -> buf1
//   ph4: A(t+2) h1    -> buf0
// Gates (before the phase's first barrier; per-wave drain + barrier => global):
//   ph3: vmcnt(ph2+ph3 loads)  => tile t+1 fully landed before ph4 reads buf1
//   ph7: vmcnt(ph6+ph7 loads)  => tile t+2 fully landed before next ph0
// Every stage targets a region whose last ds_read completed >=1 barrier-pair
// earlier (B read only at nh phases; A only at mh phases; checked per region).
// LDS XOR-swizzle: k-slot s at row r holds global slot s^(r&7); applied on the
// pre-swizzled global source (linear gload_lds dest) and on ds_read addrs.
// ACT: 0 = C += v, 1 = C += silu(v), 2 = C = v
template <int ACT, int BM>
__global__ __launch_bounds__(512, 2) void k_gemm8(const unsigned short* __restrict__ A,
                                                  const unsigned short* __restrict__ B,
                                                  float* __restrict__ C, const int ldc,
                                                  const int mtiles) {
  constexpr int HALF = BM / 2;          // rows per A half-tile
  constexpr int MI = BM / 32;           // mi frags per wave (8 or 4)
  constexpr int MQ = MI / 2;            // mi per quadrant
  constexpr int A_LOADS = HALF / 64;    // gloads per A half (2 or 1)
  constexpr int NTILE = DD / 64;        // 32 K-tiles
  constexpr int NITER = NTILE / 2;      // 16

  __shared__ unsigned short lsA[2][BM * 64];
  __shared__ unsigned short lsB[2][256 * 64];

  const int tid = threadIdx.x;
  const int lane = tid & 63, wave = tid >> 6;
  const int wm = wave >> 2, wn = wave & 3;
  const int bid = blockIdx.x;
  const int swz = (bid & 7) * (gridDim.x >> 3) + (bid >> 3);
  const int t0 = (swz % mtiles) * BM;
  const int n0 = (swz / mtiles) * 256;
  const unsigned short* Ab = A + (size_t)t0 * DD;
  const unsigned short* Bb = B + (size_t)n0 * DD;
  const int fr = lane & 15, g = lane >> 4;
  const int srow8 = tid >> 3, sslot = tid & 7;

#define STG_A(buf, h, tile)                                                         \
  { _Pragma("unroll")                                                               \
    for (int l = 0; l < A_LOADS; ++l) {                                             \
      const int rt = (h) * HALF + l * 64 + srow8;                                   \
      gload_lds16(Ab + (size_t)rt * DD + (tile) * 64 + ((sslot ^ (rt & 7)) << 3),   \
                  &lsA[buf][rt * 64 + sslot * 8]);                                  \
    } }
#define STG_B(buf, h, tile)                                                         \
  { _Pragma("unroll")                                                               \
    for (int l = 0; l < 2; ++l) {                                                   \
      const int rt = (h) * 128 + l * 64 + srow8;                                    \
      gload_lds16(Bb + (size_t)rt * DD + (tile) * 64 + ((sslot ^ (rt & 7)) << 3),   \
                  &lsB[buf][rt * 64 + sslot * 8]);                                  \
    } }
  // gate values: ph3 leaves ph2(B-pair:4)+ph3(A-h0:A_LOADS) in flight;
  //              ph7 leaves ph6(4)+ph7(2*A_LOADS) in flight.
#define VM_G3()                                                                     \
  { if constexpr (BM == 256) asm volatile("s_waitcnt vmcnt(6)" ::: "memory");       \
    else                     asm volatile("s_waitcnt vmcnt(5)" ::: "memory"); }
#define VM_G7()                                                                     \
  { if constexpr (BM == 256) asm volatile("s_waitcnt vmcnt(8)" ::: "memory");       \
    else                     asm volatile("s_waitcnt vmcnt(6)" ::: "memory"); }
#define VM_PRO()                                                                    \
  { if constexpr (BM == 256) asm volatile("s_waitcnt vmcnt(8)" ::: "memory");       \
    else                     asm volatile("s_waitcnt vmcnt(6)" ::: "memory"); }
#define VM_ZERO() asm volatile("s_waitcnt vmcnt(0)" ::: "memory")

  f32x4 acc[MI][4];
#pragma unroll
  for (int i = 0; i < MI; ++i)
#pragma unroll
    for (int j = 0; j < 4; ++j) acc[i][j] = (f32x4){0.f, 0.f, 0.f, 0.f};

  bf16x8 aF[MQ][2];      // current A quadrant [mi_local][ks]
  bf16x8 bF[2][2][2];    // both B halves [nh][ni_local][ks]

#define RD_A(buf, mi, ks)                                                           \
  (*(const bf16x8*)&lsA[buf][(wm * HALF + (mi) * 16 + fr) * 64 +                    \
                             ((((ks) * 4 + g) ^ ((wm * HALF + (mi) * 16 + fr) & 7)) << 3)])
#define RD_B(buf, ni, ks)                                                           \
  (*(const bf16x8*)&lsB[buf][(wn * 64 + (ni) * 16 + fr) * 64 +                      \
                             ((((ks) * 4 + g) ^ ((wn * 64 + (ni) * 16 + fr) & 7)) << 3)])

#define PHASE(buf, mh, nh, LA, LB, STAGES, VMK)                                     \
  {                                                                                 \
    if (LA) { _Pragma("unroll")                                                     \
      for (int q = 0; q < MQ; ++q) { _Pragma("unroll")                              \
        for (int ks = 0; ks < 2; ++ks) aF[q][ks] = RD_A(buf, (mh) * MQ + q, ks); } }\
    if (LB) { _Pragma("unroll")                                                     \
      for (int q = 0; q < 2; ++q) { _Pragma("unroll")                               \
        for (int ks = 0; ks < 2; ++ks) bF[nh][q][ks] = RD_B(buf, (nh) * 2 + q, ks); } } \
    STAGES;                                                                         \
    VMK;                                                                            \
    __builtin_amdgcn_s_barrier();                                                   \
    asm volatile("s_waitcnt lgkmcnt(0)" ::: "memory");                              \
    __builtin_amdgcn_s_setprio(1);                                                  \
    _Pragma("unroll")                                                               \
    for (int ks = 0; ks < 2; ++ks) { _Pragma("unroll")                              \
      for (int q = 0; q < MQ; ++q) { _Pragma("unroll")                              \
        for (int nq = 0; nq < 2; ++nq)                                              \
          acc[(mh) * MQ + q][(nh) * 2 + nq] = __builtin_amdgcn_mfma_f32_16x16x32_bf16( \
              aF[q][ks], bF[nh][nq][ks], acc[(mh) * MQ + q][(nh) * 2 + nq], 0, 0, 0); } } \
    __builtin_amdgcn_s_setprio(0);                                                  \
    __builtin_amdgcn_s_barrier();                                                   \
  }

  // prologue: tiles 0 (buf0) and 1 (buf1) fully staged; t0 must be landed.
  STG_B(0, 0, 0); STG_B(0, 1, 0); STG_A(0, 0, 0); STG_A(0, 1, 0);
  STG_B(1, 0, 1); STG_B(1, 1, 1); STG_A(1, 0, 1); STG_A(1, 1, 1);
  VM_PRO();
  __builtin_amdgcn_s_barrier();

  for (int i = 0; i < NITER; ++i) {
    const int T2 = 2 * i + 2, T3 = 2 * i + 3;
    const bool s2 = T2 < NTILE, s3 = T3 < NTILE;
    PHASE(0, 0, 0, true,  true,  {}, {});
    PHASE(0, 0, 1, false, true,  {}, {});
    PHASE(0, 1, 1, true,  false, { if (s2) { STG_B(0, 0, T2); STG_B(0, 1, T2); } }, {});
    PHASE(0, 1, 0, false, false, { if (s2) STG_A(0, 0, T2); },
          { if (s2) VM_G3() else VM_ZERO(); });
    PHASE(1, 0, 0, true,  true,  { if (s2) STG_A(0, 1, T2); }, {});
    PHASE(1, 0, 1, false, true,  {}, {});
    PHASE(1, 1, 1, true,  false, { if (s3) { STG_B(1, 0, T3); STG_B(1, 1, T3); } }, {});
    PHASE(1, 1, 0, false, false, { if (s3) { STG_A(1, 0, T3); STG_A(1, 1, T3); } },
          { if (s3) VM_G7() else VM_ZERO(); });
  }
#undef PHASE
#undef RD_A
#undef RD_B
#undef STG_A
#undef STG_B
#undef VM_G3
#undef VM_G7
#undef VM_PRO
#undef VM_ZERO

  // epilogue
#pragma unroll
  for (int mi = 0; mi < MI; ++mi) {
    const int orow = t0 + wm * HALF + mi * 16 + g * 4;
#pragma unroll
    for (int ni = 0; ni < 4; ++ni) {
      const int ocol = n0 + wn * 64 + ni * 16 + fr;
#pragma unroll
      for (int j = 0; j < 4; ++j) {
        const size_t idx = (size_t)(orow + j) * ldc + ocol;
        const float v = acc[mi][ni][j];
        if (ACT == 0)      C[idx] += v;
        else if (ACT == 1) C[idx] += v / (1.f + __expf(-v));
        else               C[idx] = v;
      }
    }
  }
}

// ---------------- f32 -> bf16 bulk convert ----------------
__global__ void k_cvt(const float* __restrict__ in, unsigned short* __restrict__ out, int n4) {
  int i = blockIdx.x * blockDim.x + threadIdx.x;
  const int stride = gridDim.x * blockDim.x;
  for (; i < n4; i += stride) {
    const float4 v = ((const float4*)in)[i];
    ushort4 o;
    o.x = f2bf(v.x); o.y = f2bf(v.y); o.z = f2bf(v.z); o.w = f2bf(v.w);
    ((ushort4*)out)[i] = o;
  }
}

extern "C" void kernel_launch(void* const* d_in, const int* in_sizes, int n_in,
                              void* d_out, int out_size, void* d_ws, size_t ws_size,
                              hipStream_t stream) {
  (void)in_sizes; (void)n_in; (void)out_size; (void)ws_size;
  const int* tokens = (const int*)d_in[0];
  const float* hr = (const float*)d_in[1];
  const float* hi = (const float*)d_in[2];
  const float* kar = (const float*)d_in[3];
  const float* kai = (const float*)d_in[4];
  const float* kbr = (const float*)d_in[5];
  const float* kbi = (const float*)d_in[6];
  const float* lscale = (const float*)d_in[7];
  const float* norm_w = (const float*)d_in[8];
  const float* embed = (const float*)d_in[9];
  const float* lm = (const float*)d_in[10];
  const float* fnw = (const float*)d_in[11];
  float* out = (float*)d_out;
  char* ws = (char*)d_ws;

  // ws layout: W bf16 [24][2048][2048] @0 (192 MiB); h bf16 [4096][2048] after.
  // lm_bf16 overlays W (dead after last layer). x (f32) lives in d_out (dead
  // before the final GEMM overwrites all of d_out).
  unsigned short* W = (unsigned short*)ws;
  unsigned short* h = (unsigned short*)(ws + 201326592);
  unsigned short* lmb = W;
  float* x = out;

  k_gather<<<NROWS, 256, 0, stream>>>(tokens, embed, x);
  k_wrec<<<dim3(16, 32), 256, 0, stream>>>(hr, hi, kar, kai, kbr, kbi, lscale, W);
  for (int l = 0; l < 12; ++l) {
    k_rmsnorm<<<NROWS, 256, 0, stream>>>(x, norm_w + (size_t)l * 2 * DD, h);
    k_gemm8<0, 128><<<256, 512, 0, stream>>>(h, W + (size_t)(2 * l) * DD * DD, x, DD, 32);
    k_rmsnorm<<<NROWS, 256, 0, stream>>>(x, norm_w + (size_t)l * 2 * DD + DD, h);
    k_gemm8<1, 128><<<256, 512, 0, stream>>>(h, W + (size_t)(2 * l + 1) * DD * DD, x, DD, 32);
  }
  k_rmsnorm<<<NROWS, 256, 0, stream>>>(x, fnw, h);
  k_cvt<<<2048, 256, 0, stream>>>(lm, lmb, VOCAB_N * DD / 4);
  k_gemm8<2, 256><<<2000, 512, 0, stream>>>(h, lmb, out, VOCAB_N, 16);
}

// Round 8
// 2299.224 us; speedup vs baseline: 1.6296x; 1.0198x over previous
//
#include <hip/hip_runtime.h>
#include <hip/hip_bf16.h>

#define DD 2048
#define NF 24
#define NROWS 4096
#define VOCAB_N 32000
#define EPS_F 1.1920929e-07f

typedef __attribute__((ext_vector_type(8))) __bf16 bf16x8;
typedef __attribute__((ext_vector_type(4))) float f32x4;

__device__ __forceinline__ unsigned short f2bf(float f) {
  union { float f; unsigned int u; } v; v.f = f;
  unsigned int r = v.u + 0x7fffu + ((v.u >> 16) & 1u);  // RNE
  return (unsigned short)(r >> 16);
}

__device__ __forceinline__ void gload_lds16(const void* g, void* l) {
  __builtin_amdgcn_global_load_lds(
      (const __attribute__((address_space(1))) void*)g,
      (__attribute__((address_space(3))) void*)l, 16, 0, 0);
}

// ---------------- embedding gather ----------------
__global__ __launch_bounds__(256) void k_gather(const int* __restrict__ tok,
                                                const float* __restrict__ embed,
                                                float* __restrict__ x) {
  const int row = blockIdx.x;
  const int t = tok[row];
  const float4* s = (const float4*)(embed + (size_t)t * DD);
  float4* d = (float4*)(x + (size_t)row * DD);
  d[threadIdx.x] = s[threadIdx.x];
  d[threadIdx.x + 256] = s[threadIdx.x + 256];
}

// ---------------- W reconstruction via MFMA (r5, unchanged) ----------------
__global__ __launch_bounds__(256) void k_wrec(
    const float* __restrict__ hr, const float* __restrict__ hi,
    const float* __restrict__ kar, const float* __restrict__ kai,
    const float* __restrict__ kbr, const float* __restrict__ kbi,
    const float* __restrict__ scale, unsigned short* __restrict__ W) {
  __shared__ float KAR[16][132], KAI[16][132];
  __shared__ float KBR[16][68], KBI[16][68];
  __shared__ unsigned short Wt[128][72];
  const int tid = threadIdx.x;
  const int lane = tid & 63, w = tid >> 6;
  const int fr = lane & 15, g = lane >> 4;
  const int o0 = blockIdx.x * 128, i0 = blockIdx.y * 64;

  float hrg[2][4][4], hig[2][4][4];
#pragma unroll
  for (int of = 0; of < 2; ++of)
#pragma unroll
    for (int jj = 0; jj < 4; ++jj) {
      const size_t orow = (size_t)(o0 + w * 32 + of * 16 + g * 4 + jj) * DD + i0;
#pragma unroll
      for (int fi = 0; fi < 4; ++fi) {
        hrg[of][jj][fi] = hr[orow + fi * 16 + fr];
        hig[of][jj][fi] = hi[orow + fi * 16 + fr];
      }
    }

  const int sr = tid >> 4;
  const int sca = (tid & 15) * 8;
  const int scb = (tid & 15) * 4;
  const int rlo = (g & 1) * 8;

  for (int f = 0; f < NF; ++f) {
    __syncthreads();
    {
      const size_t ga = ((size_t)f * 16 + sr) * DD;
      *(float4*)&KAR[sr][sca]     = *(const float4*)&kar[ga + o0 + sca];
      *(float4*)&KAR[sr][sca + 4] = *(const float4*)&kar[ga + o0 + sca + 4];
      *(float4*)&KAI[sr][sca]     = *(const float4*)&kai[ga + o0 + sca];
      *(float4*)&KAI[sr][sca + 4] = *(const float4*)&kai[ga + o0 + sca + 4];
      *(float4*)&KBR[sr][scb]     = *(const float4*)&kbr[ga + i0 + scb];
      *(float4*)&KBI[sr][scb]     = *(const float4*)&kbi[ga + i0 + scb];
    }
    __syncthreads();
    bf16x8 aPr[2], aPi[2], bF[4];
#pragma unroll
    for (int of = 0; of < 2; ++of) {
      const int oc = w * 32 + of * 16 + fr;
      union { bf16x8 v; unsigned short u[8]; } pu, pv;
#pragma unroll
      for (int j = 0; j < 8; ++j) {
        const float ka = KAR[rlo + j][oc];
        const float kb = KAI[rlo + j][oc];
        pu.u[j] = f2bf((g < 2) ? ka : kb);
        pv.u[j] = f2bf((g < 2) ? kb : -ka);
      }
      aPr[of] = pu.v; aPi[of] = pv.v;
    }
#pragma unroll
    for (int fi = 0; fi < 4; ++fi) {
      const int ic = fi * 16 + fr;
      union { bf16x8 v; unsigned short u[8]; } pb;
#pragma unroll
      for (int j = 0; j < 8; ++j) {
        const float vr = KBR[rlo + j][ic];
        const float vi = KBI[rlo + j][ic];
        pb.u[j] = f2bf((g < 2) ? vr : vi);
      }
      bF[fi] = pb.v;
    }
    const float sc = scale[f];
#pragma unroll
    for (int of = 0; of < 2; ++of)
#pragma unroll
      for (int fi = 0; fi < 4; ++fi) {
        const f32x4 z = (f32x4){0.f, 0.f, 0.f, 0.f};
        const f32x4 cr = __builtin_amdgcn_mfma_f32_16x16x32_bf16(aPr[of], bF[fi], z, 0, 0, 0);
        const f32x4 ci = __builtin_amdgcn_mfma_f32_16x16x32_bf16(aPi[of], bF[fi], z, 0, 0, 0);
#pragma unroll
        for (int jj = 0; jj < 4; ++jj) {
          const float wv = (hrg[of][jj][fi] * cr[jj] - hig[of][jj][fi] * ci[jj]) * sc;
          Wt[w * 32 + of * 16 + g * 4 + jj][fi * 16 + fr] = f2bf(wv);
        }
      }
    __syncthreads();
    {
      const int r = tid >> 1, hh = tid & 1;
      unsigned short* dst = W + ((size_t)f * DD + o0 + r) * DD + i0 + hh * 32;
#pragma unroll
      for (int qq = 0; qq < 4; ++qq)
        *(uint4*)(dst + qq * 8) = *(const uint4*)&Wt[r][hh * 32 + qq * 8];
    }
  }
}

// ---------------- rmsnorm ----------------
__global__ __launch_bounds__(256) void k_rmsnorm(const float* __restrict__ x,
                                                 const float* __restrict__ w,
                                                 unsigned short* __restrict__ h) {
  const int row = blockIdx.x, tid = threadIdx.x;
  const float4* xr = (const float4*)(x + (size_t)row * DD);
  const float4 a = xr[tid], b = xr[tid + 256];
  float s = a.x * a.x + a.y * a.y + a.z * a.z + a.w * a.w +
            b.x * b.x + b.y * b.y + b.z * b.z + b.w * b.w;
#pragma unroll
  for (int m = 32; m; m >>= 1) s += __shfl_xor(s, m);
  __shared__ float part[4];
  if ((tid & 63) == 0) part[tid >> 6] = s;
  __syncthreads();
  const float inv = rsqrtf((part[0] + part[1] + part[2] + part[3]) * (1.f / DD) + EPS_F);
  const float4* wr = (const float4*)w;
  const float4 w0 = wr[tid], w1 = wr[tid + 256];
  ushort4 o0, o1;
  o0.x = f2bf(a.x * inv * w0.x); o0.y = f2bf(a.y * inv * w0.y);
  o0.z = f2bf(a.z * inv * w0.z); o0.w = f2bf(a.w * inv * w0.w);
  o1.x = f2bf(b.x * inv * w1.x); o1.y = f2bf(b.y * inv * w1.y);
  o1.z = f2bf(b.z * inv * w1.z); o1.w = f2bf(b.w * inv * w1.w);
  ushort4* hd = (ushort4*)(h + (size_t)row * DD);
  hd[tid] = o0;
  hd[tid + 256] = o1;
}

// ---------------- layer GEMM: ring-3, 2 phases/K-tile, 16 MFMA/phase ----------------
// out[t][n] (+)= act( sum_k A[t][k]*B[n][k] );  BM=128, BN=256, BK=64, 8 waves
// (2M x 4N), per-wave 64x64 (MI=4, NI=4). LDS ring of 3 K-tiles:
// 3 x (A 16KB + B 32KB) = 144 KB.  Per K-tile t (slot sc=t%3, sp=(t+2)%3):
//  ph0: ds_read A(all 4 mi, 8 b128) + B(ni 0-1, 4 b128) | stage A(t+2)+B(t+2)h0
//       | barrier | lgkm0 | 16 MFMA (ni 0,1) | barrier
//  ph1: ds_read B(ni 2-3) | stage B(t+2)h1 | vmcnt(6) [tail: 0]
//       | barrier | lgkm0 | 16 MFMA (ni 2,3) | barrier
// Gate ledger: before gate, in flight = t+1's 6 + t+2's 6; vmcnt(6) retires
// t+1 (consumed next phase), keeps t+2 (lead 2-4 phases; W-panel L2-resident
// per-XCD: grid 256, XCD swizzle gives each XCD exactly one 1MB n-panel).
// Write safety: slot sp = (t-1)%3; tile t-1's last ds_read completed before its
// final barrier (lgkm0 precedes MFMA), stages issue after that rendezvous.
// Swizzle: k-slot s at row r holds global slot s^(r&7) (pre-swizzled source).
template <int ACT>
__global__ __launch_bounds__(512, 2) void k_gemmL(const unsigned short* __restrict__ A,
                                                  const unsigned short* __restrict__ B,
                                                  float* __restrict__ C) {
  constexpr int NTILE = DD / 64;  // 32
  __shared__ unsigned short lsA[3][8192];    // [slot][128 rows][64 k]
  __shared__ unsigned short lsB[3][16384];   // [slot][256 rows][64 k]
  const int tid = threadIdx.x;
  const int lane = tid & 63, wave = tid >> 6;
  const int wm = wave >> 2, wn = wave & 3;
  const int bid = blockIdx.x;
  const int swz = (bid & 7) * 32 + (bid >> 3);   // 256 blocks: XCD-contig
  const int t0 = (swz & 31) * 128;               // m-tile (32)
  const int n0 = (swz >> 5) * 256;               // n-panel (8)
  const unsigned short* Ab = A + (size_t)t0 * DD;
  const unsigned short* Bb = B + (size_t)n0 * DD;
  const int fr = lane & 15, g = lane >> 4;
  const int srow8 = tid >> 3, sslot = tid & 7;

#define LSTG_A(slot, tile)                                                          \
  { _Pragma("unroll")                                                               \
    for (int l = 0; l < 2; ++l) {                                                   \
      const int rt = l * 64 + srow8;                                                \
      gload_lds16(Ab + (size_t)rt * DD + (tile) * 64 + ((sslot ^ (rt & 7)) << 3),   \
                  &lsA[slot][rt * 64 + sslot * 8]);                                 \
    } }
#define LSTG_B(slot, h, tile)                                                       \
  { _Pragma("unroll")                                                               \
    for (int l = 0; l < 2; ++l) {                                                   \
      const int rt = (h) * 128 + l * 64 + srow8;                                    \
      gload_lds16(Bb + (size_t)rt * DD + (tile) * 64 + ((sslot ^ (rt & 7)) << 3),   \
                  &lsB[slot][rt * 64 + sslot * 8]);                                 \
    } }
#define LRD_A(slot, mi, ks)                                                         \
  (*(const bf16x8*)&lsA[slot][(wm * 64 + (mi) * 16 + fr) * 64 +                     \
                              ((((ks) * 4 + g) ^ ((wm * 64 + (mi) * 16 + fr) & 7)) << 3)])
#define LRD_B(slot, ni, ks)                                                         \
  (*(const bf16x8*)&lsB[slot][(wn * 64 + (ni) * 16 + fr) * 64 +                     \
                              ((((ks) * 4 + g) ^ ((wn * 64 + (ni) * 16 + fr) & 7)) << 3)])

  f32x4 acc[4][4];
#pragma unroll
  for (int i = 0; i < 4; ++i)
#pragma unroll
    for (int j = 0; j < 4; ++j) acc[i][j] = (f32x4){0.f, 0.f, 0.f, 0.f};

  bf16x8 aF[4][2], bF[2][2];

#define LTILE(t, sc, sp)                                                            \
  {                                                                                 \
    const bool st = (t) + 2 < NTILE;                                                \
    /* ---- phase nh0 ---- */                                                       \
    _Pragma("unroll")                                                               \
    for (int mi = 0; mi < 4; ++mi) { _Pragma("unroll")                              \
      for (int ks = 0; ks < 2; ++ks) aF[mi][ks] = LRD_A(sc, mi, ks); }              \
    _Pragma("unroll")                                                               \
    for (int q = 0; q < 2; ++q) { _Pragma("unroll")                                 \
      for (int ks = 0; ks < 2; ++ks) bF[q][ks] = LRD_B(sc, q, ks); }                \
    if (st) { LSTG_A(sp, (t) + 2); LSTG_B(sp, 0, (t) + 2); }                        \
    __builtin_amdgcn_s_barrier();                                                   \
    asm volatile("s_waitcnt lgkmcnt(0)" ::: "memory");                              \
    __builtin_amdgcn_s_setprio(1);                                                  \
    _Pragma("unroll")                                                               \
    for (int ks = 0; ks < 2; ++ks) { _Pragma("unroll")                              \
      for (int mi = 0; mi < 4; ++mi) { _Pragma("unroll")                            \
        for (int q = 0; q < 2; ++q)                                                 \
          acc[mi][q] = __builtin_amdgcn_mfma_f32_16x16x32_bf16(                     \
              aF[mi][ks], bF[q][ks], acc[mi][q], 0, 0, 0); } }                      \
    __builtin_amdgcn_s_setprio(0);                                                  \
    __builtin_amdgcn_s_barrier();                                                   \
    /* ---- phase nh1 ---- */                                                       \
    _Pragma("unroll")                                                               \
    for (int q = 0; q < 2; ++q) { _Pragma("unroll")                                 \
      for (int ks = 0; ks < 2; ++ks) bF[q][ks] = LRD_B(sc, 2 + q, ks); }            \
    if (st) LSTG_B(sp, 1, (t) + 2);                                                 \
    if (st) asm volatile("s_waitcnt vmcnt(6)" ::: "memory");                        \
    else    asm volatile("s_waitcnt vmcnt(0)" ::: "memory");                        \
    __builtin_amdgcn_s_barrier();                                                   \
    asm volatile("s_waitcnt lgkmcnt(0)" ::: "memory");                              \
    __builtin_amdgcn_s_setprio(1);                                                  \
    _Pragma("unroll")                                                               \
    for (int ks = 0; ks < 2; ++ks) { _Pragma("unroll")                              \
      for (int mi = 0; mi < 4; ++mi) { _Pragma("unroll")                            \
        for (int q = 0; q < 2; ++q)                                                 \
          acc[mi][2 + q] = __builtin_amdgcn_mfma_f32_16x16x32_bf16(                 \
              aF[mi][ks], bF[q][ks], acc[mi][2 + q], 0, 0, 0); } }                  \
    __builtin_amdgcn_s_setprio(0);                                                  \
    __builtin_amdgcn_s_barrier();                                                   \
  }

  // prologue: tiles 0,1 fully staged; ensure tile 0 landed
  LSTG_A(0, 0); LSTG_B(0, 0, 0); LSTG_B(0, 1, 0);
  LSTG_A(1, 1); LSTG_B(1, 0, 1); LSTG_B(1, 1, 1);
  asm volatile("s_waitcnt vmcnt(6)" ::: "memory");
  __builtin_amdgcn_s_barrier();

  for (int tb = 0; tb < 30; tb += 3) {
    LTILE(tb, 0, 2);
    LTILE(tb + 1, 1, 0);
    LTILE(tb + 2, 2, 1);
  }
  LTILE(30, 0, 2);
  LTILE(31, 1, 0);
#undef LTILE
#undef LRD_A
#undef LRD_B
#undef LSTG_A
#undef LSTG_B

  // epilogue
#pragma unroll
  for (int mi = 0; mi < 4; ++mi) {
    const int orow = t0 + wm * 64 + mi * 16 + g * 4;
#pragma unroll
    for (int ni = 0; ni < 4; ++ni) {
      const int ocol = n0 + wn * 64 + ni * 16 + fr;
#pragma unroll
      for (int j = 0; j < 4; ++j) {
        const size_t idx = (size_t)(orow + j) * DD + ocol;
        const float v = acc[mi][ni][j];
        if (ACT == 0) C[idx] += v;
        else          C[idx] += v / (1.f + __expf(-v));
      }
    }
  }
}

// ---------------- 8-phase GEMM for LM head (r7, frozen) ----------------
template <int ACT, int BM>
__global__ __launch_bounds__(512, 2) void k_gemm8(const unsigned short* __restrict__ A,
                                                  const unsigned short* __restrict__ B,
                                                  float* __restrict__ C, const int ldc,
                                                  const int mtiles) {
  constexpr int HALF = BM / 2;
  constexpr int MI = BM / 32;
  constexpr int MQ = MI / 2;
  constexpr int A_LOADS = HALF / 64;
  constexpr int NTILE = DD / 64;
  constexpr int NITER = NTILE / 2;

  __shared__ unsigned short lsA[2][BM * 64];
  __shared__ unsigned short lsB[2][256 * 64];

  const int tid = threadIdx.x;
  const int lane = tid & 63, wave = tid >> 6;
  const int wm = wave >> 2, wn = wave & 3;
  const int bid = blockIdx.x;
  const int swz = (bid & 7) * (gridDim.x >> 3) + (bid >> 3);
  const int t0 = (swz % mtiles) * BM;
  const int n0 = (swz / mtiles) * 256;
  const unsigned short* Ab = A + (size_t)t0 * DD;
  const unsigned short* Bb = B + (size_t)n0 * DD;
  const int fr = lane & 15, g = lane >> 4;
  const int srow8 = tid >> 3, sslot = tid & 7;

#define STG_A(buf, h, tile)                                                         \
  { _Pragma("unroll")                                                               \
    for (int l = 0; l < A_LOADS; ++l) {                                             \
      const int rt = (h) * HALF + l * 64 + srow8;                                   \
      gload_lds16(Ab + (size_t)rt * DD + (tile) * 64 + ((sslot ^ (rt & 7)) << 3),   \
                  &lsA[buf][rt * 64 + sslot * 8]);                                  \
    } }
#define STG_B(buf, h, tile)                                                         \
  { _Pragma("unroll")                                                               \
    for (int l = 0; l < 2; ++l) {                                                   \
      const int rt = (h) * 128 + l * 64 + srow8;                                    \
      gload_lds16(Bb + (size_t)rt * DD + (tile) * 64 + ((sslot ^ (rt & 7)) << 3),   \
                  &lsB[buf][rt * 64 + sslot * 8]);                                  \
    } }
#define VM_G3()                                                                     \
  { if constexpr (BM == 256) asm volatile("s_waitcnt vmcnt(6)" ::: "memory");       \
    else                     asm volatile("s_waitcnt vmcnt(5)" ::: "memory"); }
#define VM_G7()                                                                     \
  { if constexpr (BM == 256) asm volatile("s_waitcnt vmcnt(8)" ::: "memory");       \
    else                     asm volatile("s_waitcnt vmcnt(6)" ::: "memory"); }
#define VM_PRO()                                                                    \
  { if constexpr (BM == 256) asm volatile("s_waitcnt vmcnt(8)" ::: "memory");       \
    else                     asm volatile("s_waitcnt vmcnt(6)" ::: "memory"); }
#define VM_ZERO() asm volatile("s_waitcnt vmcnt(0)" ::: "memory")

  f32x4 acc[MI][4];
#pragma unroll
  for (int i = 0; i < MI; ++i)
#pragma unroll
    for (int j = 0; j < 4; ++j) acc[i][j] = (f32x4){0.f, 0.f, 0.f, 0.f};

  bf16x8 aF[MQ][2];
  bf16x8 bF[2][2][2];

#define RD_A(buf, mi, ks)                                                           \
  (*(const bf16x8*)&lsA[buf][(wm * HALF + (mi) * 16 + fr) * 64 +                    \
                             ((((ks) * 4 + g) ^ ((wm * HALF + (mi) * 16 + fr) & 7)) << 3)])
#define RD_B(buf, ni, ks)                                                           \
  (*(const bf16x8*)&lsB[buf][(wn * 64 + (ni) * 16 + fr) * 64 +                      \
                             ((((ks) * 4 + g) ^ ((wn * 64 + (ni) * 16 + fr) & 7)) << 3)])

#define PHASE(buf, mh, nh, LA, LB, STAGES, VMK)                                     \
  {                                                                                 \
    if (LA) { _Pragma("unroll")                                                     \
      for (int q = 0; q < MQ; ++q) { _Pragma("unroll")                              \
        for (int ks = 0; ks < 2; ++ks) aF[q][ks] = RD_A(buf, (mh) * MQ + q, ks); } }\
    if (LB) { _Pragma("unroll")                                                     \
      for (int q = 0; q < 2; ++q) { _Pragma("unroll")                               \
        for (int ks = 0; ks < 2; ++ks) bF[nh][q][ks] = RD_B(buf, (nh) * 2 + q, ks); } } \
    STAGES;                                                                         \
    VMK;                                                                            \
    __builtin_amdgcn_s_barrier();                                                   \
    asm volatile("s_waitcnt lgkmcnt(0)" ::: "memory");                              \
    __builtin_amdgcn_s_setprio(1);                                                  \
    _Pragma("unroll")                                                               \
    for (int ks = 0; ks < 2; ++ks) { _Pragma("unroll")                              \
      for (int q = 0; q < MQ; ++q) { _Pragma("unroll")                              \
        for (int nq = 0; nq < 2; ++nq)                                              \
          acc[(mh) * MQ + q][(nh) * 2 + nq] = __builtin_amdgcn_mfma_f32_16x16x32_bf16( \
              aF[q][ks], bF[nh][nq][ks], acc[(mh) * MQ + q][(nh) * 2 + nq], 0, 0, 0); } } \
    __builtin_amdgcn_s_setprio(0);                                                  \
    __builtin_amdgcn_s_barrier();                                                   \
  }

  STG_B(0, 0, 0); STG_B(0, 1, 0); STG_A(0, 0, 0); STG_A(0, 1, 0);
  STG_B(1, 0, 1); STG_B(1, 1, 1); STG_A(1, 0, 1); STG_A(1, 1, 1);
  VM_PRO();
  __builtin_amdgcn_s_barrier();

  for (int i = 0; i < NITER; ++i) {
    const int T2 = 2 * i + 2, T3 = 2 * i + 3;
    const bool s2 = T2 < NTILE, s3 = T3 < NTILE;
    PHASE(0, 0, 0, true,  true,  {}, {});
    PHASE(0, 0, 1, false, true,  {}, {});
    PHASE(0, 1, 1, true,  false, { if (s2) { STG_B(0, 0, T2); STG_B(0, 1, T2); } }, {});
    PHASE(0, 1, 0, false, false, { if (s2) STG_A(0, 0, T2); },
          { if (s2) VM_G3() else VM_ZERO(); });
    PHASE(1, 0, 0, true,  true,  { if (s2) STG_A(0, 1, T2); }, {});
    PHASE(1, 0, 1, false, true,  {}, {});
    PHASE(1, 1, 1, true,  false, { if (s3) { STG_B(1, 0, T3); STG_B(1, 1, T3); } }, {});
    PHASE(1, 1, 0, false, false, { if (s3) { STG_A(1, 0, T3); STG_A(1, 1, T3); } },
          { if (s3) VM_G7() else VM_ZERO(); });
  }
#undef PHASE
#undef RD_A
#undef RD_B
#undef STG_A
#undef STG_B
#undef VM_G3
#undef VM_G7
#undef VM_PRO
#undef VM_ZERO

#pragma unroll
  for (int mi = 0; mi < MI; ++mi) {
    const int orow = t0 + wm * HALF + mi * 16 + g * 4;
#pragma unroll
    for (int ni = 0; ni < 4; ++ni) {
      const int ocol = n0 + wn * 64 + ni * 16 + fr;
#pragma unroll
      for (int j = 0; j < 4; ++j) {
        const size_t idx = (size_t)(orow + j) * ldc + ocol;
        const float v = acc[mi][ni][j];
        if (ACT == 0)      C[idx] += v;
        else if (ACT == 1) C[idx] += v / (1.f + __expf(-v));
        else               C[idx] = v;
      }
    }
  }
}

// ---------------- f32 -> bf16 bulk convert ----------------
__global__ void k_cvt(const float* __restrict__ in, unsigned short* __restrict__ out, int n4) {
  int i = blockIdx.x * blockDim.x + threadIdx.x;
  const int stride = gridDim.x * blockDim.x;
  for (; i < n4; i += stride) {
    const float4 v = ((const float4*)in)[i];
    ushort4 o;
    o.x = f2bf(v.x); o.y = f2bf(v.y); o.z = f2bf(v.z); o.w = f2bf(v.w);
    ((ushort4*)out)[i] = o;
  }
}

extern "C" void kernel_launch(void* const* d_in, const int* in_sizes, int n_in,
                              void* d_out, int out_size, void* d_ws, size_t ws_size,
                              hipStream_t stream) {
  (void)in_sizes; (void)n_in; (void)out_size; (void)ws_size;
  const int* tokens = (const int*)d_in[0];
  const float* hr = (const float*)d_in[1];
  const float* hi = (const float*)d_in[2];
  const float* kar = (const float*)d_in[3];
  const float* kai = (const float*)d_in[4];
  const float* kbr = (const float*)d_in[5];
  const float* kbi = (const float*)d_in[6];
  const float* lscale = (const float*)d_in[7];
  const float* norm_w = (const float*)d_in[8];
  const float* embed = (const float*)d_in[9];
  const float* lm = (const float*)d_in[10];
  const float* fnw = (const float*)d_in[11];
  float* out = (float*)d_out;
  char* ws = (char*)d_ws;

  // ws layout: W bf16 [24][2048][2048] @0 (192 MiB); h bf16 [4096][2048] after.
  // lm_bf16 overlays W (dead after last layer). x (f32) lives in d_out (dead
  // before the final GEMM overwrites all of d_out).
  unsigned short* W = (unsigned short*)ws;
  unsigned short* h = (unsigned short*)(ws + 201326592);
  unsigned short* lmb = W;
  float* x = out;

  k_gather<<<NROWS, 256, 0, stream>>>(tokens, embed, x);
  k_wrec<<<dim3(16, 32), 256, 0, stream>>>(hr, hi, kar, kai, kbr, kbi, lscale, W);
  for (int l = 0; l < 12; ++l) {
    k_rmsnorm<<<NROWS, 256, 0, stream>>>(x, norm_w + (size_t)l * 2 * DD, h);
    k_gemmL<0><<<256, 512, 0, stream>>>(h, W + (size_t)(2 * l) * DD * DD, x);
    k_rmsnorm<<<NROWS, 256, 0, stream>>>(x, norm_w + (size_t)l * 2 * DD + DD, h);
    k_gemmL<1><<<256, 512, 0, stream>>>(h, W + (size_t)(2 * l + 1) * DD * DD, x);
  }
  k_rmsnorm<<<NROWS, 256, 0, stream>>>(x, fnw, h);
  k_cvt<<<2048, 256, 0, stream>>>(lm, lmb, VOCAB_N * DD / 4);
  k_gemm8<2, 256><<<2000, 512, 0, stream>>>(h, lmb, out, VOCAB_N, 16);
}